// Round 9
// baseline (691.116 us; speedup 1.0000x reference)
//
#include <hip/hip_runtime.h>

// LightGCN-style 2-layer propagation, N=100000, D=64, NNZ=1.6M per matrix.
// Round 9: R8 structure, tuned. pass1 tile 4096->2048 (LDS 48->27KB, 3->5
// blocks/CU: latency-bound kernel, occupancy is the lever). cat_l0 writes
// t(=e1) once (B0 is dead after L0's first spmm; reuse it as t/e1 buffer).

#define RPB   256        // rows per bucket (bucket = row >> 8)
#define P1T   2048       // edges per pass-1 tile (LDS 27KB -> 5 blocks/CU)
#define NBINS 512        // LDS bin arrays (NB <= 512 required)

typedef float          f32x4  __attribute__((ext_vector_type(4)));
typedef int            i32x2  __attribute__((ext_vector_type(2)));
typedef unsigned short u16x4v __attribute__((ext_vector_type(4)));

#define TF_ROUND(x0, x1, r) { x0 += x1; x1 = ((x1 << r) | (x1 >> (32 - r))); x1 ^= x0; }

__host__ __device__ inline void threefry2x32(unsigned k0, unsigned k1,
                                             unsigned& x0, unsigned& x1) {
  unsigned k2 = k0 ^ k1 ^ 0x1BD11BDAu;
  x0 += k0; x1 += k1;
  TF_ROUND(x0, x1, 13) TF_ROUND(x0, x1, 15) TF_ROUND(x0, x1, 26) TF_ROUND(x0, x1, 6)
  x0 += k1; x1 += k2 + 1u;
  TF_ROUND(x0, x1, 17) TF_ROUND(x0, x1, 29) TF_ROUND(x0, x1, 16) TF_ROUND(x0, x1, 24)
  x0 += k2; x1 += k0 + 2u;
  TF_ROUND(x0, x1, 13) TF_ROUND(x0, x1, 15) TF_ROUND(x0, x1, 26) TF_ROUND(x0, x1, 6)
  x0 += k0; x1 += k1 + 3u;
  TF_ROUND(x0, x1, 17) TF_ROUND(x0, x1, 29) TF_ROUND(x0, x1, 16) TF_ROUND(x0, x1, 24)
  x0 += k1; x1 += k2 + 4u;
  TF_ROUND(x0, x1, 13) TF_ROUND(x0, x1, 15) TF_ROUND(x0, x1, 26) TF_ROUND(x0, x1, 6)
  x0 += k2; x1 += k0 + 5u;
}

__device__ inline float drop1(float val, unsigned k0, unsigned k1, unsigned idx) {
  unsigned x0 = 0u, x1 = idx;            // counter (hi, lo) = (0, linear idx)
  threefry2x32(k0, k1, x0, x1);
  unsigned bits = x0 ^ x1;               // partitionable 32-bit draw
  float u = __uint_as_float(0x3F800000u | (bits >> 9)) - 1.0f;
  return (u < 0.9f) ? val * (1.0f / 0.9f) : 0.0f;
}

__device__ inline unsigned short f2bf(float f) {   // RNE f32->bf16
  unsigned u = __float_as_uint(f);
  unsigned r = 0x7FFFu + ((u >> 16) & 1u);
  return (unsigned short)((u + r) >> 16);
}
__device__ inline float bf2f(unsigned short h) {
  return __uint_as_float((unsigned)h << 16);
}
__device__ inline u16x4v pack4(float a, float b, float c, float d) {
  u16x4v r; r.x = f2bf(a); r.y = f2bf(b); r.z = f2bf(c); r.w = f2bf(d); return r;
}
__device__ inline int2 nt_load_pair(const int2* p) {
  i32x2 t = __builtin_nontemporal_load((const i32x2*)p);
  return make_int2(t.x, t.y);
}

// ================= pass 1: bucketize all 5 matrices, one dispatch ==========
// Entry = int2( col | (rl<<24), val ); rl = row & 255 (RPB=256, col < 2^24).

struct P1Arr {
  const int* rows[5]; const int* cols[5]; const float* vals[5];
  int nnz[5]; int bb[6];
};

__global__ void __launch_bounds__(256) pass1_all(
    P1Arr ba, int* __restrict__ g_bcnt, int2* __restrict__ gP,
    long pStride, int NB, int CAP) {
  __shared__ int bin_cnt[NBINS], bin_pos[NBINS], bin_base[NBINS], tsc[256];
  __shared__ unsigned short sBin[P1T];
  __shared__ int2 sP[P1T];
  int tid = threadIdx.x;
  int blk = blockIdx.x;
  int m = 0;
  while (m < 4 && blk >= ba.bb[m + 1]) ++m;
  int t0 = (blk - ba.bb[m]) * P1T;
  int tn = ba.nnz[m] - t0; if (tn > P1T) tn = P1T;
  const int* rows = ba.rows[m];
  const int* cols = ba.cols[m];
  const float* vals = ba.vals[m];
  bin_cnt[tid] = 0; bin_cnt[tid + 256] = 0;
  __syncthreads();
  for (int k = tid; k < tn; k += 256)
    atomicAdd(&bin_cnt[rows[t0 + k] >> 8], 1);
  __syncthreads();
  int a0 = bin_cnt[2 * tid], a1 = bin_cnt[2 * tid + 1];
  int s2 = a0 + a1;
  tsc[tid] = s2;
  __syncthreads();
  for (int off = 1; off < 256; off <<= 1) {
    int x = (tid >= off) ? tsc[tid - off] : 0;
    __syncthreads();
    tsc[tid] += x;
    __syncthreads();
  }
  int excl = tsc[tid] - s2;
  bin_pos[2 * tid] = excl;
  bin_pos[2 * tid + 1] = excl + a0;
  int* bc = g_bcnt + m * NBINS;
  bin_base[2 * tid]     = a0 ? atomicAdd(&bc[2 * tid], a0)     : 0;
  bin_base[2 * tid + 1] = a1 ? atomicAdd(&bc[2 * tid + 1], a1) : 0;
  bin_cnt[2 * tid] = 0; bin_cnt[2 * tid + 1] = 0;
  __syncthreads();
  for (int k = tid; k < tn; k += 256) {
    int e = t0 + k;
    int r = rows[e];
    int b = r >> 8;
    int idx = bin_pos[b] + atomicAdd(&bin_cnt[b], 1);
    sBin[idx] = (unsigned short)b;
    sP[idx] = make_int2(cols[e] | ((r & 255) << 24), __float_as_int(vals[e]));
  }
  __syncthreads();
  int2* gPm = gP + (size_t)m * pStride;
  for (int j = tid; j < tn; j += 256) {
    int b = sBin[j];
    int off = bin_base[b] + (j - bin_pos[b]);
    if (off < CAP)                        // statistically never (12 sigma)
      gPm[(size_t)b * CAP + off] = sP[j];
  }
}

// ================= pass 2: in-place per-bucket row sort + int2 rowp ========

struct P2Arr { int2* rowp[5]; };

__global__ void __launch_bounds__(256) pass2_all(
    const int* __restrict__ g_bcnt, int2* __restrict__ gP,
    P2Arr pa, long pStride, int N, int NB, int CAP) {
  extern __shared__ int2 sP[];           // CAP entries (LDS stage)
  __shared__ int rp[256], fillc[256], tsc[256];
  int tid = threadIdx.x;
  int b = blockIdx.x, m = blockIdx.y;
  int cnt = g_bcnt[m * NBINS + b]; if (cnt > CAP) cnt = CAP;
  int2* win = gP + (size_t)m * pStride + (size_t)b * CAP;
  for (int i = tid; i < cnt; i += 256) sP[i] = win[i];
  rp[tid] = 0; fillc[tid] = 0;
  __syncthreads();
  for (int i = tid; i < cnt; i += 256)
    atomicAdd(&rp[((unsigned)sP[i].x) >> 24], 1);   // int LDS atomic: native
  __syncthreads();
  int v = rp[tid];
  tsc[tid] = v;
  __syncthreads();
  for (int off = 1; off < 256; off <<= 1) {
    int x = (tid >= off) ? tsc[tid - off] : 0;
    __syncthreads();
    tsc[tid] += x;
    __syncthreads();
  }
  int ex = tsc[tid] - v;
  __syncthreads();
  rp[tid] = ex;
  int r0 = b << 8;
  int row = r0 + tid;
  int base = b * CAP;
  if (row < N) pa.rowp[m][row] = make_int2(base + ex, base + ex + v);
  __syncthreads();
  for (int i = tid; i < cnt; i += 256) {
    unsigned ux = (unsigned)sP[i].x;
    int lr = (int)(ux >> 24);
    int pos = rp[lr] + atomicAdd(&fillc[lr], 1);
    win[pos] = make_int2((int)(ux & 0xFFFFFFu), sP[i].y);  // strip rl
  }
}

// ================= h0 f32 -> interleaved bf16 [N][128] =================

__global__ void __launch_bounds__(256) conv_h0_kernel(
    const float4* __restrict__ h0u, const float4* __restrict__ h0i,
    u16x4v* __restrict__ B0, int N) {
  int tid = blockIdx.x * 256 + threadIdx.x;
  int row = tid >> 5, sub = tid & 31;
  if (row >= N) return;
  int s16 = sub & 15;
  float4 v = (sub < 16) ? h0u[(size_t)row * 16 + s16] : h0i[(size_t)row * 16 + s16];
  B0[(size_t)row * 32 + sub] = pack4(v.x, v.y, v.z, v.w);
}

// ================= dual-path bf16 SpMM (register accumulate) ==============

struct HalfB { const int2* rowp; const int2* pairs; };

__global__ void __launch_bounds__(256) spmm_dual_bf16_kernel(
    HalfB A, HalfB B, const u16x4v* __restrict__ x,
    u16x4v* __restrict__ out, int N) {
  int tid = blockIdx.x * 256 + threadIdx.x;
  int halfsz = N * 16;
  bool second = tid >= halfsz;
  int t2 = second ? tid - halfsz : tid;
  if (t2 >= halfsz) return;
  const int2* rowp  = second ? B.rowp  : A.rowp;
  const int2* pairs = second ? B.pairs : A.pairs;
  int ho = second ? 16 : 0;
  int row = t2 >> 4, sub = t2 & 15;
  int2 se = rowp[row];
  int s = se.x, e = se.y;
  float4 acc = {0.f, 0.f, 0.f, 0.f};
  #pragma unroll 4
  for (int i = s; i < e; ++i) {
    int2 p = nt_load_pair(&pairs[i]);
    float v = __int_as_float(p.y);
    u16x4v xv = x[(size_t)p.x * 32 + ho + sub];
    acc.x += v * bf2f(xv.x); acc.y += v * bf2f(xv.y);
    acc.z += v * bf2f(xv.z); acc.w += v * bf2f(xv.w);
  }
  __builtin_nontemporal_store(pack4(acc.x, acc.y, acc.z, acc.w),
                              &out[(size_t)row * 32 + ho + sub]);
}

// ================= cat (bf16 in) + dropout =================

__global__ void __launch_bounds__(256) cat_l0_kernel(
    const int2* __restrict__ rowp, const int2* __restrict__ pairs,
    const u16x4v* __restrict__ x, u16x4v* __restrict__ t_out,
    unsigned k0u, unsigned k1u, unsigned k0i, unsigned k1i, int N) {
  int tid = blockIdx.x * 256 + threadIdx.x;
  int row = tid >> 5, sub = tid & 31;
  if (row >= N) return;
  int2 se = rowp[row];
  int s = se.x, e = se.y;
  float4 acc = {0.f, 0.f, 0.f, 0.f};
  #pragma unroll 4
  for (int i = s; i < e; ++i) {
    int2 p = nt_load_pair(&pairs[i]);
    float v = __int_as_float(p.y);
    u16x4v xv = x[(size_t)p.x * 32 + sub];
    acc.x += v * bf2f(xv.x); acc.y += v * bf2f(xv.y);
    acc.z += v * bf2f(xv.z); acc.w += v * bf2f(xv.w);
  }
  int s16 = sub & 15;
  bool isI = sub >= 16;
  unsigned k0 = isI ? k0i : k0u, k1 = isI ? k1i : k1u;
  unsigned base = (unsigned)row * 64u + (unsigned)s16 * 4u;
  float4 t;
  t.x = drop1(acc.x, k0, k1, base + 0u);
  t.y = drop1(acc.y, k0, k1, base + 1u);
  t.z = drop1(acc.z, k0, k1, base + 2u);
  t.w = drop1(acc.w, k0, k1, base + 3u);
  // t == e1: single store (consumed as layer-1 input AND by cat_final)
  __builtin_nontemporal_store(pack4(t.x, t.y, t.z, t.w),
                              &t_out[(size_t)row * 32 + sub]);
}

__global__ void __launch_bounds__(256) cat_final_kernel(
    const int2* __restrict__ rowp, const int2* __restrict__ pairs,
    const u16x4v* __restrict__ x, const u16x4v* __restrict__ e1buf,
    const float4* __restrict__ h0_u, const float4* __restrict__ h0_i,
    float4* __restrict__ out_u, float4* __restrict__ out_i,
    unsigned k0u, unsigned k1u, unsigned k0i, unsigned k1i, int N) {
  int tid = blockIdx.x * 256 + threadIdx.x;
  int row = tid >> 5, sub = tid & 31;
  if (row >= N) return;
  int2 se = rowp[row];
  int s = se.x, e = se.y;
  float4 acc = {0.f, 0.f, 0.f, 0.f};
  #pragma unroll 4
  for (int i = s; i < e; ++i) {
    int2 p = nt_load_pair(&pairs[i]);
    float v = __int_as_float(p.y);
    u16x4v xv = x[(size_t)p.x * 32 + sub];
    acc.x += v * bf2f(xv.x); acc.y += v * bf2f(xv.y);
    acc.z += v * bf2f(xv.z); acc.w += v * bf2f(xv.w);
  }
  int s16 = sub & 15;
  bool isI = sub >= 16;
  unsigned k0 = isI ? k0i : k0u, k1 = isI ? k1i : k1u;
  unsigned base = (unsigned)row * 64u + (unsigned)s16 * 4u;
  float4 t;
  t.x = drop1(acc.x, k0, k1, base + 0u);
  t.y = drop1(acc.y, k0, k1, base + 1u);
  t.z = drop1(acc.z, k0, k1, base + 2u);
  t.w = drop1(acc.w, k0, k1, base + 3u);
  u16x4v e1 = e1buf[(size_t)row * 32 + sub];
  const float4* h0 = isI ? h0_i : h0_u;
  float4* oh = isI ? out_i : out_u;
  size_t o = (size_t)row * 16 + s16;
  float4 hv = h0[o];
  f32x4 res;
  res.x = (hv.x + bf2f(e1.x) + t.x) * (1.0f / 3.0f);
  res.y = (hv.y + bf2f(e1.y) + t.y) * (1.0f / 3.0f);
  res.z = (hv.z + bf2f(e1.z) + t.z) * (1.0f / 3.0f);
  res.w = (hv.w + bf2f(e1.w) + t.w) * (1.0f / 3.0f);
  __builtin_nontemporal_store(res, (f32x4*)&oh[o]);
}

// ================= atomic fallback (R2, ws-too-small safety net) ==========

__global__ void __launch_bounds__(256) spmm_atomic_kernel(
    const int* __restrict__ rows, const int* __restrict__ cols,
    const float* __restrict__ vals, const float* __restrict__ x,
    float* __restrict__ out, int nnz) {
  long tid = (long)blockIdx.x * blockDim.x + threadIdx.x;
  long edge = tid >> 4;
  int sub = (int)(tid & 15);
  if (edge >= nnz) return;
  int r = rows[edge];
  int c = cols[edge];
  float v = vals[edge];
  float4 xv = reinterpret_cast<const float4*>(x)[(long)c * 16 + sub];
  float* o = out + (long)r * 64 + (long)sub * 4;
  atomicAdd(o + 0, v * xv.x);
  atomicAdd(o + 1, v * xv.y);
  atomicAdd(o + 2, v * xv.z);
  atomicAdd(o + 3, v * xv.w);
}

__global__ void __launch_bounds__(256) dropout_acc_kernel(
    float* __restrict__ t, float* __restrict__ acc,
    unsigned k0, unsigned k1, int n) {
  int idx = blockIdx.x * blockDim.x + threadIdx.x;
  if (idx >= n) return;
  float e = drop1(t[idx], k0, k1, (unsigned)idx);
  t[idx] = e;
  acc[idx] += e;
}

__global__ void __launch_bounds__(256) scale4_kernel(float* __restrict__ o, float s, int n4) {
  int i = blockIdx.x * 256 + threadIdx.x;
  if (i >= n4) return;
  float4 v = reinterpret_cast<float4*>(o)[i];
  v.x *= s; v.y *= s; v.z *= s; v.w *= s;
  reinterpret_cast<float4*>(o)[i] = v;
}

// ================= launcher =================

struct Coo { const int* r; const int* c; const float* v; int nnz; };

extern "C" void kernel_launch(void* const* d_in, const int* in_sizes, int n_in,
                              void* d_out, int out_size, void* d_ws, size_t ws_size,
                              hipStream_t stream) {
  const float* user_emb = (const float*)d_in[0];
  const float* item_emb = (const float*)d_in[1];
  enum { U1 = 0, U2 = 1, I1 = 2, I2 = 3, CAT = 4 };
  Coo mats[5] = {
    { (const int*)d_in[2],  (const int*)d_in[3],  (const float*)d_in[4],  in_sizes[2]  },
    { (const int*)d_in[5],  (const int*)d_in[6],  (const float*)d_in[7],  in_sizes[5]  },
    { (const int*)d_in[8],  (const int*)d_in[9],  (const float*)d_in[10], in_sizes[8]  },
    { (const int*)d_in[11], (const int*)d_in[12], (const float*)d_in[13], in_sizes[11] },
    { (const int*)d_in[14], (const int*)d_in[15], (const float*)d_in[16], in_sizes[14] },
  };

  const int ND = in_sizes[0];        // N * 64
  const int N = ND / 64;
  const int NB = (N + RPB - 1) / RPB;

  float* out_u = (float*)d_out;
  float* out_i = out_u + ND;

  unsigned keys[4][2];
  for (unsigned d = 0; d < 4; ++d) {
    unsigned x0 = 0u, x1 = d;
    threefry2x32(0u, 50u, x0, x1);
    keys[d][0] = x0; keys[d][1] = x1;
  }

  auto AL = [](size_t b) { return (b + 255) & ~255ULL; };
  size_t maxnnz = 0;
  for (int m = 0; m < 5; ++m)
    if ((size_t)mats[m].nnz > maxnnz) maxnnz = (size_t)mats[m].nnz;

  // bucket capacity ~ mean + mean/16 + 384 (>= 12 sigma of Binomial(nnz,1/NB))
  size_t avg = maxnnz / (size_t)NB;
  size_t CAP = (avg + avg / 16 + 384 + 255) & ~255ULL;
  size_t CAPTOT = CAP * (size_t)NB;
  size_t pStride = AL(CAPTOT * 8) / 8;      // int2 elements per matrix plane

  const size_t needA = 3 * AL((size_t)N * 256) +      // B0,B1,B2 bf16 [N][128]
                       AL(5 * NBINS * 4) +            // bucket counts
                       5 * AL((size_t)N * 8) +        // int2 rowp per matrix
                       5 * AL(CAPTOT * 8);            // padded pair planes

  if (NB <= NBINS && ws_size >= needA && N <= (1 << 24)) {
    char* p = (char*)d_ws;
    auto take = [&](size_t bytes) { char* q = p; p += (bytes + 255) & ~255ULL; return (void*)q; };
    u16x4v* B0 = (u16x4v*)take((size_t)N * 256);
    u16x4v* B1 = (u16x4v*)take((size_t)N * 256);
    u16x4v* B2 = (u16x4v*)take((size_t)N * 256);
    int* g_bcnt = (int*)take(5 * NBINS * 4);
    P2Arr pa;
    for (int m = 0; m < 5; ++m) pa.rowp[m] = (int2*)take((size_t)N * 8);
    int2* gP = (int2*)take(5 * AL(CAPTOT * 8));

    hipMemsetAsync(g_bcnt, 0, 5 * NBINS * 4, stream);

    P1Arr ba;
    int bbTot = 0;
    for (int m = 0; m < 5; ++m) {
      ba.rows[m] = mats[m].r; ba.cols[m] = mats[m].c; ba.vals[m] = mats[m].v;
      ba.nnz[m] = mats[m].nnz; ba.bb[m] = bbTot;
      bbTot += (mats[m].nnz + P1T - 1) / P1T;
    }
    ba.bb[5] = bbTot;
    pass1_all<<<bbTot, 256, 0, stream>>>(ba, g_bcnt, gP, (long)pStride, NB, (int)CAP);
    dim3 g2(NB, 5);
    pass2_all<<<g2, 256, CAP * 8, stream>>>(g_bcnt, gP, pa, (long)pStride, N, NB, (int)CAP);

    const int sgrid = (2 * N * 16 + 255) / 256;
    const int cgrid = (N * 32 + 255) / 256;
    const float4* h0u4 = (const float4*)user_emb;
    const float4* h0i4 = (const float4*)item_emb;

    conv_h0_kernel<<<cgrid, 256, 0, stream>>>(h0u4, h0i4, B0, N);

    auto PM = [&](int m) { return (const int2*)(gP + (size_t)m * pStride); };

    // ---- layer 0 ----  B0 -> B1 -> B2 ; cat_l0: B2 -> B0 (t == e1, one store)
    { HalfB a{pa.rowp[U2], PM(U2)}, b{pa.rowp[I2], PM(I2)};
      spmm_dual_bf16_kernel<<<sgrid, 256, 0, stream>>>(a, b, B0, B1, N); }
    { HalfB a{pa.rowp[U1], PM(U1)}, b{pa.rowp[I1], PM(I1)};
      spmm_dual_bf16_kernel<<<sgrid, 256, 0, stream>>>(a, b, B1, B2, N); }
    cat_l0_kernel<<<cgrid, 256, 0, stream>>>(pa.rowp[CAT], PM(CAT), B2, B0,
                                             keys[0][0], keys[0][1], keys[2][0], keys[2][1], N);
    // ---- layer 1 ----  B0 -> B1 -> B2 ; cat_final: B2 (+e1:B0, h0 f32) -> out
    { HalfB a{pa.rowp[U2], PM(U2)}, b{pa.rowp[I2], PM(I2)};
      spmm_dual_bf16_kernel<<<sgrid, 256, 0, stream>>>(a, b, B0, B1, N); }
    { HalfB a{pa.rowp[U1], PM(U1)}, b{pa.rowp[I1], PM(I1)};
      spmm_dual_bf16_kernel<<<sgrid, 256, 0, stream>>>(a, b, B1, B2, N); }
    cat_final_kernel<<<cgrid, 256, 0, stream>>>(pa.rowp[CAT], PM(CAT), B2, B0,
                                                h0u4, h0i4, (float4*)out_u, (float4*)out_i,
                                                keys[1][0], keys[1][1], keys[3][0], keys[3][1], N);
    return;
  }

  // ---- atomic fallback (R2) ----
  float* B1 = (float*)d_ws;
  float* B2 = B1 + ND;
  float* B3 = B2 + ND;
  auto spmm = [&](const Coo& m, const float* x, float* o) {
    hipMemsetAsync(o, 0, (size_t)ND * sizeof(float), stream);
    long threads = (long)m.nnz * 16;
    spmm_atomic_kernel<<<(int)((threads + 255) / 256), 256, 0, stream>>>(
        m.r, m.c, m.v, x, o, m.nnz);
  };
  const int dgrid = (ND + 255) / 256;
  for (int path = 0; path < 2; ++path) {
    const float* h0 = path ? item_emb : user_emb;
    float* acc = path ? out_i : out_u;
    const Coo& A2 = mats[path ? I2 : U2];
    const Coo& A1 = mats[path ? I1 : U1];
    hipMemcpyAsync(acc, h0, (size_t)ND * sizeof(float), hipMemcpyDeviceToDevice, stream);
    const float* in = h0;
    for (int li = 0; li < 2; ++li) {
      spmm(A2, in, B1);
      spmm(A1, B1, B2);
      spmm(mats[CAT], B2, B3);
      int d = path * 2 + li;
      dropout_acc_kernel<<<dgrid, 256, 0, stream>>>(B3, acc, keys[d][0], keys[d][1], ND);
      in = B3;
    }
  }
  const int n4 = (2 * ND) / 4;
  scale4_kernel<<<(n4 + 255) / 256, 256, 0, stream>>>((float*)d_out, 1.0f / 3.0f, n4);
}

// Round 10
// 665.392 us; speedup vs baseline: 1.0387x; 1.0387x over previous
//
#include <hip/hip_runtime.h>

// LightGCN-style 2-layer propagation, N=100000, D=64, NNZ=1.6M per matrix.
// Round 10: pass1 with packed-meta LDS (4B/edge instead of 14B): scatter phase
// stores (k<<17)|(b<<8)|rl; flush re-reads cols/vals from the L1-hot 16KB tile
// window. P1T=4096 (long runs, amortized scans), LDS 23.5KB -> 6 blocks/CU.
// Rest = R9 (CSR bucket build, bf16 dual SpMM, fused cat/dropout/mean).

#define RPB   256        // rows per bucket (bucket = row >> 8)
#define P1T   4096       // edges per pass-1 tile (k fits 12 bits)
#define NBINS 512        // LDS bin arrays (NB <= 512 required)

typedef float          f32x4  __attribute__((ext_vector_type(4)));
typedef int            i32x2  __attribute__((ext_vector_type(2)));
typedef unsigned short u16x4v __attribute__((ext_vector_type(4)));

#define TF_ROUND(x0, x1, r) { x0 += x1; x1 = ((x1 << r) | (x1 >> (32 - r))); x1 ^= x0; }

__host__ __device__ inline void threefry2x32(unsigned k0, unsigned k1,
                                             unsigned& x0, unsigned& x1) {
  unsigned k2 = k0 ^ k1 ^ 0x1BD11BDAu;
  x0 += k0; x1 += k1;
  TF_ROUND(x0, x1, 13) TF_ROUND(x0, x1, 15) TF_ROUND(x0, x1, 26) TF_ROUND(x0, x1, 6)
  x0 += k1; x1 += k2 + 1u;
  TF_ROUND(x0, x1, 17) TF_ROUND(x0, x1, 29) TF_ROUND(x0, x1, 16) TF_ROUND(x0, x1, 24)
  x0 += k2; x1 += k0 + 2u;
  TF_ROUND(x0, x1, 13) TF_ROUND(x0, x1, 15) TF_ROUND(x0, x1, 26) TF_ROUND(x0, x1, 6)
  x0 += k0; x1 += k1 + 3u;
  TF_ROUND(x0, x1, 17) TF_ROUND(x0, x1, 29) TF_ROUND(x0, x1, 16) TF_ROUND(x0, x1, 24)
  x0 += k1; x1 += k2 + 4u;
  TF_ROUND(x0, x1, 13) TF_ROUND(x0, x1, 15) TF_ROUND(x0, x1, 26) TF_ROUND(x0, x1, 6)
  x0 += k2; x1 += k0 + 5u;
}

__device__ inline float drop1(float val, unsigned k0, unsigned k1, unsigned idx) {
  unsigned x0 = 0u, x1 = idx;            // counter (hi, lo) = (0, linear idx)
  threefry2x32(k0, k1, x0, x1);
  unsigned bits = x0 ^ x1;               // partitionable 32-bit draw
  float u = __uint_as_float(0x3F800000u | (bits >> 9)) - 1.0f;
  return (u < 0.9f) ? val * (1.0f / 0.9f) : 0.0f;
}

__device__ inline unsigned short f2bf(float f) {   // RNE f32->bf16
  unsigned u = __float_as_uint(f);
  unsigned r = 0x7FFFu + ((u >> 16) & 1u);
  return (unsigned short)((u + r) >> 16);
}
__device__ inline float bf2f(unsigned short h) {
  return __uint_as_float((unsigned)h << 16);
}
__device__ inline u16x4v pack4(float a, float b, float c, float d) {
  u16x4v r; r.x = f2bf(a); r.y = f2bf(b); r.z = f2bf(c); r.w = f2bf(d); return r;
}
__device__ inline int2 nt_load_pair(const int2* p) {
  i32x2 t = __builtin_nontemporal_load((const i32x2*)p);
  return make_int2(t.x, t.y);
}

// ================= pass 1: bucketize all 5 matrices, one dispatch ==========
// Plane entry = int2( col | (rl<<24), val ); rl = row & 255.
// LDS meta = (k<<17) | (b<<8) | rl  — 4B/edge; cols/vals re-read at flush.

struct P1Arr {
  const int* rows[5]; const int* cols[5]; const float* vals[5];
  int nnz[5]; int bb[6];
};

__global__ void __launch_bounds__(256) pass1_all(
    P1Arr ba, int* __restrict__ g_bcnt, int2* __restrict__ gP,
    long pStride, int NB, int CAP) {
  __shared__ int bin_cnt[NBINS], bin_pos[NBINS], bin_base[NBINS], tsc[256];
  __shared__ unsigned sMeta[P1T];
  int tid = threadIdx.x;
  int blk = blockIdx.x;
  int m = 0;
  while (m < 4 && blk >= ba.bb[m + 1]) ++m;
  int t0 = (blk - ba.bb[m]) * P1T;
  int tn = ba.nnz[m] - t0; if (tn > P1T) tn = P1T;
  const int* rows = ba.rows[m];
  const int* cols = ba.cols[m];
  const float* vals = ba.vals[m];
  bin_cnt[tid] = 0; bin_cnt[tid + 256] = 0;
  __syncthreads();
  // count bins (coalesced rows read)
  for (int k = tid; k < tn; k += 256)
    atomicAdd(&bin_cnt[rows[t0 + k] >> 8], 1);
  __syncthreads();
  // exclusive scan of 512 bins (2/thread) + global space reservation
  int a0 = bin_cnt[2 * tid], a1 = bin_cnt[2 * tid + 1];
  int s2 = a0 + a1;
  tsc[tid] = s2;
  __syncthreads();
  for (int off = 1; off < 256; off <<= 1) {
    int x = (tid >= off) ? tsc[tid - off] : 0;
    __syncthreads();
    tsc[tid] += x;
    __syncthreads();
  }
  int excl = tsc[tid] - s2;
  bin_pos[2 * tid] = excl;
  bin_pos[2 * tid + 1] = excl + a0;
  int* bc = g_bcnt + m * NBINS;
  bin_base[2 * tid]     = a0 ? atomicAdd(&bc[2 * tid], a0)     : 0;
  bin_base[2 * tid + 1] = a1 ? atomicAdd(&bc[2 * tid + 1], a1) : 0;
  bin_cnt[2 * tid] = 0; bin_cnt[2 * tid + 1] = 0;
  __syncthreads();
  // scatter packed meta into bucket-sorted LDS order (4B/edge)
  for (int k = tid; k < tn; k += 256) {
    int r = rows[t0 + k];                 // L1-hot second read
    int b = r >> 8;
    int idx = bin_pos[b] + atomicAdd(&bin_cnt[b], 1);
    sMeta[idx] = ((unsigned)k << 17) | ((unsigned)b << 8) | (unsigned)(r & 255);
  }
  __syncthreads();
  // flush coalesced runs; cols/vals re-read randomly within 16KB L1-hot window
  int2* gPm = gP + (size_t)m * pStride;
  for (int j = tid; j < tn; j += 256) {
    unsigned mt = sMeta[j];
    int rl = (int)(mt & 255u);
    int b  = (int)((mt >> 8) & 511u);
    int k  = (int)(mt >> 17);
    int off = bin_base[b] + (j - bin_pos[b]);
    if (off < CAP) {                      // statistically never (12 sigma)
      int e = t0 + k;
      gPm[(size_t)b * CAP + off] =
          make_int2(cols[e] | (rl << 24), __float_as_int(vals[e]));
    }
  }
}

// ================= pass 2: in-place per-bucket row sort + int2 rowp ========

struct P2Arr { int2* rowp[5]; };

__global__ void __launch_bounds__(256) pass2_all(
    const int* __restrict__ g_bcnt, int2* __restrict__ gP,
    P2Arr pa, long pStride, int N, int NB, int CAP) {
  extern __shared__ int2 sP[];           // CAP entries (LDS stage)
  __shared__ int rp[256], fillc[256], tsc[256];
  int tid = threadIdx.x;
  int b = blockIdx.x, m = blockIdx.y;
  int cnt = g_bcnt[m * NBINS + b]; if (cnt > CAP) cnt = CAP;
  int2* win = gP + (size_t)m * pStride + (size_t)b * CAP;
  for (int i = tid; i < cnt; i += 256) sP[i] = win[i];
  rp[tid] = 0; fillc[tid] = 0;
  __syncthreads();
  for (int i = tid; i < cnt; i += 256)
    atomicAdd(&rp[((unsigned)sP[i].x) >> 24], 1);   // int LDS atomic: native
  __syncthreads();
  int v = rp[tid];
  tsc[tid] = v;
  __syncthreads();
  for (int off = 1; off < 256; off <<= 1) {
    int x = (tid >= off) ? tsc[tid - off] : 0;
    __syncthreads();
    tsc[tid] += x;
    __syncthreads();
  }
  int ex = tsc[tid] - v;
  __syncthreads();
  rp[tid] = ex;
  int r0 = b << 8;
  int row = r0 + tid;
  int base = b * CAP;
  if (row < N) pa.rowp[m][row] = make_int2(base + ex, base + ex + v);
  __syncthreads();
  for (int i = tid; i < cnt; i += 256) {
    unsigned ux = (unsigned)sP[i].x;
    int lr = (int)(ux >> 24);
    int pos = rp[lr] + atomicAdd(&fillc[lr], 1);
    win[pos] = make_int2((int)(ux & 0xFFFFFFu), sP[i].y);  // strip rl
  }
}

// ================= h0 f32 -> interleaved bf16 [N][128] =================

__global__ void __launch_bounds__(256) conv_h0_kernel(
    const float4* __restrict__ h0u, const float4* __restrict__ h0i,
    u16x4v* __restrict__ B0, int N) {
  int tid = blockIdx.x * 256 + threadIdx.x;
  int row = tid >> 5, sub = tid & 31;
  if (row >= N) return;
  int s16 = sub & 15;
  float4 v = (sub < 16) ? h0u[(size_t)row * 16 + s16] : h0i[(size_t)row * 16 + s16];
  B0[(size_t)row * 32 + sub] = pack4(v.x, v.y, v.z, v.w);
}

// ================= dual-path bf16 SpMM (register accumulate) ==============

struct HalfB { const int2* rowp; const int2* pairs; };

__global__ void __launch_bounds__(256) spmm_dual_bf16_kernel(
    HalfB A, HalfB B, const u16x4v* __restrict__ x,
    u16x4v* __restrict__ out, int N) {
  int tid = blockIdx.x * 256 + threadIdx.x;
  int halfsz = N * 16;
  bool second = tid >= halfsz;
  int t2 = second ? tid - halfsz : tid;
  if (t2 >= halfsz) return;
  const int2* rowp  = second ? B.rowp  : A.rowp;
  const int2* pairs = second ? B.pairs : A.pairs;
  int ho = second ? 16 : 0;
  int row = t2 >> 4, sub = t2 & 15;
  int2 se = rowp[row];
  int s = se.x, e = se.y;
  float4 acc = {0.f, 0.f, 0.f, 0.f};
  #pragma unroll 4
  for (int i = s; i < e; ++i) {
    int2 p = nt_load_pair(&pairs[i]);
    float v = __int_as_float(p.y);
    u16x4v xv = x[(size_t)p.x * 32 + ho + sub];
    acc.x += v * bf2f(xv.x); acc.y += v * bf2f(xv.y);
    acc.z += v * bf2f(xv.z); acc.w += v * bf2f(xv.w);
  }
  __builtin_nontemporal_store(pack4(acc.x, acc.y, acc.z, acc.w),
                              &out[(size_t)row * 32 + ho + sub]);
}

// ================= cat (bf16 in) + dropout =================

__global__ void __launch_bounds__(256) cat_l0_kernel(
    const int2* __restrict__ rowp, const int2* __restrict__ pairs,
    const u16x4v* __restrict__ x, u16x4v* __restrict__ t_out,
    unsigned k0u, unsigned k1u, unsigned k0i, unsigned k1i, int N) {
  int tid = blockIdx.x * 256 + threadIdx.x;
  int row = tid >> 5, sub = tid & 31;
  if (row >= N) return;
  int2 se = rowp[row];
  int s = se.x, e = se.y;
  float4 acc = {0.f, 0.f, 0.f, 0.f};
  #pragma unroll 4
  for (int i = s; i < e; ++i) {
    int2 p = nt_load_pair(&pairs[i]);
    float v = __int_as_float(p.y);
    u16x4v xv = x[(size_t)p.x * 32 + sub];
    acc.x += v * bf2f(xv.x); acc.y += v * bf2f(xv.y);
    acc.z += v * bf2f(xv.z); acc.w += v * bf2f(xv.w);
  }
  int s16 = sub & 15;
  bool isI = sub >= 16;
  unsigned k0 = isI ? k0i : k0u, k1 = isI ? k1i : k1u;
  unsigned base = (unsigned)row * 64u + (unsigned)s16 * 4u;
  float4 t;
  t.x = drop1(acc.x, k0, k1, base + 0u);
  t.y = drop1(acc.y, k0, k1, base + 1u);
  t.z = drop1(acc.z, k0, k1, base + 2u);
  t.w = drop1(acc.w, k0, k1, base + 3u);
  // t == e1: single store (consumed as layer-1 input AND by cat_final)
  __builtin_nontemporal_store(pack4(t.x, t.y, t.z, t.w),
                              &t_out[(size_t)row * 32 + sub]);
}

__global__ void __launch_bounds__(256) cat_final_kernel(
    const int2* __restrict__ rowp, const int2* __restrict__ pairs,
    const u16x4v* __restrict__ x, const u16x4v* __restrict__ e1buf,
    const float4* __restrict__ h0_u, const float4* __restrict__ h0_i,
    float4* __restrict__ out_u, float4* __restrict__ out_i,
    unsigned k0u, unsigned k1u, unsigned k0i, unsigned k1i, int N) {
  int tid = blockIdx.x * 256 + threadIdx.x;
  int row = tid >> 5, sub = tid & 31;
  if (row >= N) return;
  int2 se = rowp[row];
  int s = se.x, e = se.y;
  float4 acc = {0.f, 0.f, 0.f, 0.f};
  #pragma unroll 4
  for (int i = s; i < e; ++i) {
    int2 p = nt_load_pair(&pairs[i]);
    float v = __int_as_float(p.y);
    u16x4v xv = x[(size_t)p.x * 32 + sub];
    acc.x += v * bf2f(xv.x); acc.y += v * bf2f(xv.y);
    acc.z += v * bf2f(xv.z); acc.w += v * bf2f(xv.w);
  }
  int s16 = sub & 15;
  bool isI = sub >= 16;
  unsigned k0 = isI ? k0i : k0u, k1 = isI ? k1i : k1u;
  unsigned base = (unsigned)row * 64u + (unsigned)s16 * 4u;
  float4 t;
  t.x = drop1(acc.x, k0, k1, base + 0u);
  t.y = drop1(acc.y, k0, k1, base + 1u);
  t.z = drop1(acc.z, k0, k1, base + 2u);
  t.w = drop1(acc.w, k0, k1, base + 3u);
  u16x4v e1 = e1buf[(size_t)row * 32 + sub];
  const float4* h0 = isI ? h0_i : h0_u;
  float4* oh = isI ? out_i : out_u;
  size_t o = (size_t)row * 16 + s16;
  float4 hv = h0[o];
  f32x4 res;
  res.x = (hv.x + bf2f(e1.x) + t.x) * (1.0f / 3.0f);
  res.y = (hv.y + bf2f(e1.y) + t.y) * (1.0f / 3.0f);
  res.z = (hv.z + bf2f(e1.z) + t.z) * (1.0f / 3.0f);
  res.w = (hv.w + bf2f(e1.w) + t.w) * (1.0f / 3.0f);
  __builtin_nontemporal_store(res, (f32x4*)&oh[o]);
}

// ================= atomic fallback (R2, ws-too-small safety net) ==========

__global__ void __launch_bounds__(256) spmm_atomic_kernel(
    const int* __restrict__ rows, const int* __restrict__ cols,
    const float* __restrict__ vals, const float* __restrict__ x,
    float* __restrict__ out, int nnz) {
  long tid = (long)blockIdx.x * blockDim.x + threadIdx.x;
  long edge = tid >> 4;
  int sub = (int)(tid & 15);
  if (edge >= nnz) return;
  int r = rows[edge];
  int c = cols[edge];
  float v = vals[edge];
  float4 xv = reinterpret_cast<const float4*>(x)[(long)c * 16 + sub];
  float* o = out + (long)r * 64 + (long)sub * 4;
  atomicAdd(o + 0, v * xv.x);
  atomicAdd(o + 1, v * xv.y);
  atomicAdd(o + 2, v * xv.z);
  atomicAdd(o + 3, v * xv.w);
}

__global__ void __launch_bounds__(256) dropout_acc_kernel(
    float* __restrict__ t, float* __restrict__ acc,
    unsigned k0, unsigned k1, int n) {
  int idx = blockIdx.x * blockDim.x + threadIdx.x;
  if (idx >= n) return;
  float e = drop1(t[idx], k0, k1, (unsigned)idx);
  t[idx] = e;
  acc[idx] += e;
}

__global__ void __launch_bounds__(256) scale4_kernel(float* __restrict__ o, float s, int n4) {
  int i = blockIdx.x * 256 + threadIdx.x;
  if (i >= n4) return;
  float4 v = reinterpret_cast<float4*>(o)[i];
  v.x *= s; v.y *= s; v.z *= s; v.w *= s;
  reinterpret_cast<float4*>(o)[i] = v;
}

// ================= launcher =================

struct Coo { const int* r; const int* c; const float* v; int nnz; };

extern "C" void kernel_launch(void* const* d_in, const int* in_sizes, int n_in,
                              void* d_out, int out_size, void* d_ws, size_t ws_size,
                              hipStream_t stream) {
  const float* user_emb = (const float*)d_in[0];
  const float* item_emb = (const float*)d_in[1];
  enum { U1 = 0, U2 = 1, I1 = 2, I2 = 3, CAT = 4 };
  Coo mats[5] = {
    { (const int*)d_in[2],  (const int*)d_in[3],  (const float*)d_in[4],  in_sizes[2]  },
    { (const int*)d_in[5],  (const int*)d_in[6],  (const float*)d_in[7],  in_sizes[5]  },
    { (const int*)d_in[8],  (const int*)d_in[9],  (const float*)d_in[10], in_sizes[8]  },
    { (const int*)d_in[11], (const int*)d_in[12], (const float*)d_in[13], in_sizes[11] },
    { (const int*)d_in[14], (const int*)d_in[15], (const float*)d_in[16], in_sizes[14] },
  };

  const int ND = in_sizes[0];        // N * 64
  const int N = ND / 64;
  const int NB = (N + RPB - 1) / RPB;

  float* out_u = (float*)d_out;
  float* out_i = out_u + ND;

  unsigned keys[4][2];
  for (unsigned d = 0; d < 4; ++d) {
    unsigned x0 = 0u, x1 = d;
    threefry2x32(0u, 50u, x0, x1);
    keys[d][0] = x0; keys[d][1] = x1;
  }

  auto AL = [](size_t b) { return (b + 255) & ~255ULL; };
  size_t maxnnz = 0;
  for (int m = 0; m < 5; ++m)
    if ((size_t)mats[m].nnz > maxnnz) maxnnz = (size_t)mats[m].nnz;

  // bucket capacity ~ mean + mean/16 + 384 (>= 12 sigma of Binomial(nnz,1/NB))
  size_t avg = maxnnz / (size_t)NB;
  size_t CAP = (avg + avg / 16 + 384 + 255) & ~255ULL;
  size_t CAPTOT = CAP * (size_t)NB;
  size_t pStride = AL(CAPTOT * 8) / 8;      // int2 elements per matrix plane

  const size_t needA = 3 * AL((size_t)N * 256) +      // B0,B1,B2 bf16 [N][128]
                       AL(5 * NBINS * 4) +            // bucket counts
                       5 * AL((size_t)N * 8) +        // int2 rowp per matrix
                       5 * AL(CAPTOT * 8);            // padded pair planes

  if (NB <= NBINS && ws_size >= needA && N <= (1 << 24)) {
    char* p = (char*)d_ws;
    auto take = [&](size_t bytes) { char* q = p; p += (bytes + 255) & ~255ULL; return (void*)q; };
    u16x4v* B0 = (u16x4v*)take((size_t)N * 256);
    u16x4v* B1 = (u16x4v*)take((size_t)N * 256);
    u16x4v* B2 = (u16x4v*)take((size_t)N * 256);
    int* g_bcnt = (int*)take(5 * NBINS * 4);
    P2Arr pa;
    for (int m = 0; m < 5; ++m) pa.rowp[m] = (int2*)take((size_t)N * 8);
    int2* gP = (int2*)take(5 * AL(CAPTOT * 8));

    hipMemsetAsync(g_bcnt, 0, 5 * NBINS * 4, stream);

    P1Arr ba;
    int bbTot = 0;
    for (int m = 0; m < 5; ++m) {
      ba.rows[m] = mats[m].r; ba.cols[m] = mats[m].c; ba.vals[m] = mats[m].v;
      ba.nnz[m] = mats[m].nnz; ba.bb[m] = bbTot;
      bbTot += (mats[m].nnz + P1T - 1) / P1T;
    }
    ba.bb[5] = bbTot;
    pass1_all<<<bbTot, 256, 0, stream>>>(ba, g_bcnt, gP, (long)pStride, NB, (int)CAP);
    dim3 g2(NB, 5);
    pass2_all<<<g2, 256, CAP * 8, stream>>>(g_bcnt, gP, pa, (long)pStride, N, NB, (int)CAP);

    const int sgrid = (2 * N * 16 + 255) / 256;
    const int cgrid = (N * 32 + 255) / 256;
    const float4* h0u4 = (const float4*)user_emb;
    const float4* h0i4 = (const float4*)item_emb;

    conv_h0_kernel<<<cgrid, 256, 0, stream>>>(h0u4, h0i4, B0, N);

    auto PM = [&](int m) { return (const int2*)(gP + (size_t)m * pStride); };

    // ---- layer 0 ----  B0 -> B1 -> B2 ; cat_l0: B2 -> B0 (t == e1, one store)
    { HalfB a{pa.rowp[U2], PM(U2)}, b{pa.rowp[I2], PM(I2)};
      spmm_dual_bf16_kernel<<<sgrid, 256, 0, stream>>>(a, b, B0, B1, N); }
    { HalfB a{pa.rowp[U1], PM(U1)}, b{pa.rowp[I1], PM(I1)};
      spmm_dual_bf16_kernel<<<sgrid, 256, 0, stream>>>(a, b, B1, B2, N); }
    cat_l0_kernel<<<cgrid, 256, 0, stream>>>(pa.rowp[CAT], PM(CAT), B2, B0,
                                             keys[0][0], keys[0][1], keys[2][0], keys[2][1], N);
    // ---- layer 1 ----  B0 -> B1 -> B2 ; cat_final: B2 (+e1:B0, h0 f32) -> out
    { HalfB a{pa.rowp[U2], PM(U2)}, b{pa.rowp[I2], PM(I2)};
      spmm_dual_bf16_kernel<<<sgrid, 256, 0, stream>>>(a, b, B0, B1, N); }
    { HalfB a{pa.rowp[U1], PM(U1)}, b{pa.rowp[I1], PM(I1)};
      spmm_dual_bf16_kernel<<<sgrid, 256, 0, stream>>>(a, b, B1, B2, N); }
    cat_final_kernel<<<cgrid, 256, 0, stream>>>(pa.rowp[CAT], PM(CAT), B2, B0,
                                                h0u4, h0i4, (float4*)out_u, (float4*)out_i,
                                                keys[1][0], keys[1][1], keys[3][0], keys[3][1], N);
    return;
  }

  // ---- atomic fallback (R2) ----
  float* B1 = (float*)d_ws;
  float* B2 = B1 + ND;
  float* B3 = B2 + ND;
  auto spmm = [&](const Coo& m, const float* x, float* o) {
    hipMemsetAsync(o, 0, (size_t)ND * sizeof(float), stream);
    long threads = (long)m.nnz * 16;
    spmm_atomic_kernel<<<(int)((threads + 255) / 256), 256, 0, stream>>>(
        m.r, m.c, m.v, x, o, m.nnz);
  };
  const int dgrid = (ND + 255) / 256;
  for (int path = 0; path < 2; ++path) {
    const float* h0 = path ? item_emb : user_emb;
    float* acc = path ? out_i : out_u;
    const Coo& A2 = mats[path ? I2 : U2];
    const Coo& A1 = mats[path ? I1 : U1];
    hipMemcpyAsync(acc, h0, (size_t)ND * sizeof(float), hipMemcpyDeviceToDevice, stream);
    const float* in = h0;
    for (int li = 0; li < 2; ++li) {
      spmm(A2, in, B1);
      spmm(A1, B1, B2);
      spmm(mats[CAT], B2, B3);
      int d = path * 2 + li;
      dropout_acc_kernel<<<dgrid, 256, 0, stream>>>(B3, acc, keys[d][0], keys[d][1], ND);
      in = B3;
    }
  }
  const int n4 = (2 * ND) / 4;
  scale4_kernel<<<(n4 + 255) / 256, 256, 0, stream>>>((float*)d_out, 1.0f / 3.0f, n4);
}